// Round 3
// baseline (318.114 us; speedup 1.0000x reference)
//
#include <hip/hip_runtime.h>
#include <stdint.h>

// LeNet5-XNOR fused pipeline, round 3.
// vs round 2: conv1_sign does 2 pooled positions/thread with aligned float4
// patch loads (better s_load amortization); conv2lin processes 2 images per
// block (denser phases, halved barrier/weight-staging cost per image, fc via
// wave shuffle reduction).

#define NIMG 8192

// ---------------- workspace layout ----------------
// 0      : 1024 f32   T (summed image)
// 4096   : 20 f32     mean
// 4224   : 1250 u32   packed conv2 weight sign masks (bit = ic)
// 9344   : 500 f32    alpha_l
// 11392  : 500*20 u64 packed sign(lin_w) rows
// 91392  : 8192*196 u32 stage-1 channel masks

__global__ __launch_bounds__(64) void prep_k(const float* __restrict__ lw,
                                             const float* __restrict__ w2,
                                             unsigned long long* __restrict__ lwp,
                                             float* __restrict__ alpha,
                                             uint32_t* __restrict__ wp2) {
  int b = blockIdx.x, t = threadIdx.x;
  if (b < 500) {
    int j = b;
    float pa = 0.f;
    for (int k = t; k < 1250; k += 64) pa += fabsf(lw[j * 1250 + k]);
    for (int o = 32; o > 0; o >>= 1) pa += __shfl_down(pa, o, 64);
    if (t == 0) alpha[j] = pa / 1250.0f;
    if (t < 20) {
      unsigned long long m = 0;
      int base = j * 1250 + t * 64;
      int lim = 1250 - t * 64; if (lim > 64) lim = 64;
      for (int bb = 0; bb < lim; ++bb)
        if (lw[base + bb] > 0.f) m |= (1ull << bb);
      lwp[j * 20 + t] = m;
    }
  } else {
    int idx = (b - 500) * 64 + t;
    if (idx < 1250) {
      int oc = idx / 25, k = idx % 25;
      uint32_t m = 0;
      for (int ic = 0; ic < 20; ++ic)
        if (w2[(oc * 20 + ic) * 25 + k] > 0.f) m |= (1u << ic);
      wp2[idx] = m;
    }
  }
}

__global__ __launch_bounds__(256) void sumT_k(const float* __restrict__ x,
                                              float* __restrict__ T) {
  int b = blockIdx.x, t = threadIdx.x;
  const float4* xv = (const float4*)x + (size_t)b * 32 * 256;
  float ax = 0.f, ay = 0.f, az = 0.f, aw = 0.f;
  for (int nn = 0; nn < 32; ++nn) {
    float4 v = xv[nn * 256 + t];
    ax += v.x; ay += v.y; az += v.z; aw += v.w;
  }
  atomicAdd(&T[t * 4 + 0], ax);
  atomicAdd(&T[t * 4 + 1], ay);
  atomicAdd(&T[t * 4 + 2], az);
  atomicAdd(&T[t * 4 + 3], aw);
}

__global__ void mean_k(const float* __restrict__ T, const float* __restrict__ w1,
                       float* __restrict__ mean) {
  __shared__ double U[25];
  int t = threadIdx.x;
  if (t < 25) {
    int ky = t / 5, kx = t % 5;
    double s = 0.0;
    for (int py = 0; py < 28; ++py)
      for (int px = 0; px < 28; ++px)
        s += (double)T[(py + ky) * 32 + px + kx];
    U[t] = s;
  }
  __syncthreads();
  if (t < 20) {
    double s = 0.0;
    for (int q = 0; q < 25; ++q) s += (double)w1[t * 25 + q] * U[q];
    mean[t] = (float)(s / (8192.0 * 784.0));
  }
}

// thread = (n, py, px-pair): 2 pooled outputs (8 conv positions) per thread.
// Patch 6x8 via aligned float4 loads. 8192*98/256 = 3136 blocks exactly.
__global__ __launch_bounds__(256) void conv1_sign_k(const float* __restrict__ x,
                                                    const float* __restrict__ w1,
                                                    const float* __restrict__ mean,
                                                    uint32_t* __restrict__ b1p) {
  unsigned gid = blockIdx.x * 256 + threadIdx.x;  // < 8192*98 exactly
  unsigned n = gid / 98u;
  unsigned u = gid % 98u;
  unsigned py = u / 7u, pxp = u % 7u;
  const float* base = x + (size_t)n * 1024 + py * 64 + pxp * 4;
  float p[6][8];
#pragma unroll
  for (int r = 0; r < 6; ++r) {
    float4 a = *(const float4*)(base + r * 32);
    float4 b = *(const float4*)(base + r * 32 + 4);
    p[r][0] = a.x; p[r][1] = a.y; p[r][2] = a.z; p[r][3] = a.w;
    p[r][4] = b.x; p[r][5] = b.y; p[r][6] = b.z; p[r][7] = b.w;
  }
  uint32_t mask0 = 0, mask1 = 0;
  for (int c = 0; c < 20; ++c) {
    float s[2][4];
#pragma unroll
    for (int dy = 0; dy < 2; ++dy)
#pragma unroll
      for (int dx = 0; dx < 4; ++dx) s[dy][dx] = 0.f;
#pragma unroll
    for (int ky = 0; ky < 5; ++ky)
#pragma unroll
      for (int kx = 0; kx < 5; ++kx) {
        float wv = w1[c * 25 + ky * 5 + kx];
#pragma unroll
        for (int dy = 0; dy < 2; ++dy)
#pragma unroll
          for (int dx = 0; dx < 4; ++dx)
            s[dy][dx] += p[ky + dy][kx + dx] * wv;
      }
    float m = mean[c];
    if (s[0][0] > m || s[0][1] > m || s[1][0] > m || s[1][1] > m) mask0 |= (1u << c);
    if (s[0][2] > m || s[0][3] > m || s[1][2] > m || s[1][3] > m) mask1 |= (1u << c);
  }
  uint2 st; st.x = mask0; st.y = mask1;
  *(uint2*)(b1p + (size_t)n * 196 + py * 14 + pxp * 2) = st;
}

// Fused conv2+pool/sign+linear+fc, 2 images per block.
__global__ __launch_bounds__(256) void conv2lin_k(const uint32_t* __restrict__ b1p,
                                                  const uint32_t* __restrict__ wp2,
                                                  const unsigned long long* __restrict__ lwp,
                                                  const float* __restrict__ alpha,
                                                  const float* __restrict__ fcw,
                                                  const float* __restrict__ fcb,
                                                  float* __restrict__ out) {
  __shared__ uint32_t bm[2][196];
  __shared__ int sp[2][196];
  __shared__ int sumpc[2][100];
  __shared__ uint32_t wsh[1250];
  __shared__ signed char s2sh[2][1280];
  __shared__ unsigned long long Pm[2][20], Nm[2][20];
  __shared__ int cnts[2][2];
  __shared__ float hsh[2][500];
  int n0 = blockIdx.x * 2, tid = threadIdx.x;

  for (int i = tid; i < 392; i += 256) {
    int img = i / 196, pos = i % 196;
    uint32_t v = b1p[(size_t)(n0 + img) * 196 + pos];
    bm[img][pos] = v;
    sp[img][pos] = __popc(v);
  }
  for (int i = tid; i < 1250; i += 256) wsh[i] = wp2[i];
  if (tid < 60) {
    int img = tid / 30, k = tid % 30;
    s2sh[img][1250 + k] = 0;
  }
  __syncthreads();

  if (tid < 200) {
    int img = tid / 100, p = tid % 100;
    int y = p / 10, xx = p % 10, s = 0;
#pragma unroll
    for (int ky = 0; ky < 5; ++ky)
#pragma unroll
      for (int kx = 0; kx < 5; ++kx)
        s += sp[img][(y + ky) * 14 + xx + kx];
    sumpc[img][p] = s;
  }
  __syncthreads();

  // conv2: unit = (img, oc, pooled row)
  for (int uu = tid; uu < 500; uu += 256) {
    int img = uu / 250, t = uu % 250;
    int oc = t / 5, r = t % 5;
    uint32_t w[25];
#pragma unroll
    for (int i = 0; i < 25; ++i) w[i] = wsh[oc * 25 + i];
    uint32_t pa[6][14];
#pragma unroll
    for (int rr = 0; rr < 6; ++rr)
      for (int cc = 0; cc < 14; ++cc)
        pa[rr][cc] = bm[img][(2 * r + rr) * 14 + cc];
    for (int c = 0; c < 5; ++c) {
      int best = -1000000;
#pragma unroll
      for (int dy = 0; dy < 2; ++dy)
#pragma unroll
        for (int dx = 0; dx < 2; ++dx) {
          int ux = 2 * c + dx;
          int a = 0;
#pragma unroll
          for (int ky = 0; ky < 5; ++ky)
#pragma unroll
            for (int kx = 0; kx < 5; ++kx)
              a += __popc(w[ky * 5 + kx] & pa[dy + ky][ux + kx]);
          a = 2 * a - sumpc[img][(2 * r + dy) * 10 + ux];
          if (a > best) best = a;
        }
      s2sh[img][oc * 25 + r * 5 + c] = (signed char)((best > 0) - (best < 0));
    }
  }
  __syncthreads();

  // pack signs via ballot: 2560 entries = 10 full passes
  const signed char* s2flat = (const signed char*)s2sh;
#pragma unroll
  for (int p = 0; p < 10; ++p) {
    int idx = p * 256 + tid;
    int v = s2flat[idx];
    unsigned long long P = __ballot(v > 0);
    unsigned long long N = __ballot(v < 0);
    if ((tid & 63) == 0) {
      int word = idx >> 6;
      int img = word / 20, w = word % 20;
      Pm[img][w] = P; Nm[img][w] = N;
    }
  }
  __syncthreads();
  if (tid < 2) {
    int cp = 0, cn = 0;
    for (int i = 0; i < 20; ++i) { cp += __popcll(Pm[tid][i]); cn += __popcll(Nm[tid][i]); }
    cnts[tid][0] = cp; cnts[tid][1] = cn;
  }
  __syncthreads();

  // binary linear 1250->500 + clip, 1000 units
  for (int uu = tid; uu < 1000; uu += 256) {
    int img = uu / 500, j = uu % 500;
    const ulonglong2* W2 = (const ulonglong2*)(lwp + (size_t)j * 20);
    int a = 0, b = 0;
#pragma unroll
    for (int i = 0; i < 10; ++i) {
      ulonglong2 w2v = W2[i];
      a += __popcll(w2v.x & Pm[img][2 * i]) + __popcll(w2v.y & Pm[img][2 * i + 1]);
      b += __popcll(w2v.x & Nm[img][2 * i]) + __popcll(w2v.y & Nm[img][2 * i + 1]);
    }
    int dot = 2 * (a - b) - cnts[img][0] + cnts[img][1];
    float y = alpha[j] * (float)dot;
    hsh[img][j] = fminf(1.0f, fmaxf(-1.0f, y));
  }
  __syncthreads();

  // fc 500->10 for both images: unit = (img, o, lane8), shuffle reduce
  if (tid < 160) {
    int img = tid / 80, t = tid % 80;
    int o = t / 8, l = t & 7;
    float pa = 0.f;
    for (int j = l; j < 500; j += 8) pa += hsh[img][j] * fcw[o * 500 + j];
    pa += __shfl_down(pa, 4, 64);
    pa += __shfl_down(pa, 2, 64);
    pa += __shfl_down(pa, 1, 64);
    if (l == 0) out[(size_t)(n0 + img) * 10 + o] = pa + fcb[o];
  }
}

extern "C" void kernel_launch(void* const* d_in, const int* in_sizes, int n_in,
                              void* d_out, int out_size, void* d_ws, size_t ws_size,
                              hipStream_t stream) {
  const float* x   = (const float*)d_in[0];
  const float* w1  = (const float*)d_in[1];
  const float* w2  = (const float*)d_in[2];
  const float* lw  = (const float*)d_in[3];
  const float* fcw = (const float*)d_in[4];
  const float* fcb = (const float*)d_in[5];
  float* out = (float*)d_out;
  char* ws = (char*)d_ws;

  float*    T     = (float*)(ws + 0);
  float*    mean  = (float*)(ws + 4096);
  uint32_t* wp2   = (uint32_t*)(ws + 4224);
  float*    alpha = (float*)(ws + 9344);
  unsigned long long* lwp = (unsigned long long*)(ws + 11392);
  uint32_t* b1p   = (uint32_t*)(ws + 91392);

  hipMemsetAsync(T, 0, 1024 * sizeof(float), stream);
  prep_k<<<520, 64, 0, stream>>>(lw, w2, lwp, alpha, wp2);
  sumT_k<<<256, 256, 0, stream>>>(x, T);
  mean_k<<<1, 64, 0, stream>>>(T, w1, mean);
  conv1_sign_k<<<3136, 256, 0, stream>>>(x, w1, mean, b1p);
  conv2lin_k<<<4096, 256, 0, stream>>>(b1p, wp2, lwp, alpha, fcw, fcb, out);
}

// Round 4
// 283.558 us; speedup vs baseline: 1.1219x; 1.1219x over previous
//
#include <hip/hip_runtime.h>
#include <stdint.h>

// LeNet5-XNOR fused pipeline, round 4.
// vs round 3:
//  - conv2lin: wave-per-image (block = 4 images). One barrier total; ballot
//    results (wave-uniform) carry the P/N masks in registers; pa[6][6] per
//    pooled output cuts VGPRs.
//  - conv1_sign: 2x2 pooled outputs per thread (8x8 patch), 400 fma per
//    25 scalar weight loads.
//  - mean_k parallelized.

#define NIMG 8192

__global__ __launch_bounds__(64) void prep_k(const float* __restrict__ lw,
                                             const float* __restrict__ w2,
                                             unsigned long long* __restrict__ lwp,
                                             float* __restrict__ alpha,
                                             uint32_t* __restrict__ wp2) {
  int b = blockIdx.x, t = threadIdx.x;
  if (b < 500) {
    int j = b;
    float pa = 0.f;
    for (int k = t; k < 1250; k += 64) pa += fabsf(lw[j * 1250 + k]);
    for (int o = 32; o > 0; o >>= 1) pa += __shfl_down(pa, o, 64);
    if (t == 0) alpha[j] = pa / 1250.0f;
    if (t < 20) {
      unsigned long long m = 0;
      int base = j * 1250 + t * 64;
      int lim = 1250 - t * 64; if (lim > 64) lim = 64;
      for (int bb = 0; bb < lim; ++bb)
        if (lw[base + bb] > 0.f) m |= (1ull << bb);
      lwp[j * 20 + t] = m;
    }
  } else {
    int idx = (b - 500) * 64 + t;
    if (idx < 1250) {
      int oc = idx / 25, k = idx % 25;
      uint32_t m = 0;
      for (int ic = 0; ic < 20; ++ic)
        if (w2[(oc * 20 + ic) * 25 + k] > 0.f) m |= (1u << ic);
      wp2[idx] = m;
    }
  }
}

__global__ __launch_bounds__(256) void sumT_k(const float* __restrict__ x,
                                              float* __restrict__ T) {
  int b = blockIdx.x, t = threadIdx.x;
  const float4* xv = (const float4*)x + (size_t)b * 32 * 256;
  float ax = 0.f, ay = 0.f, az = 0.f, aw = 0.f;
  for (int nn = 0; nn < 32; ++nn) {
    float4 v = xv[nn * 256 + t];
    ax += v.x; ay += v.y; az += v.z; aw += v.w;
  }
  atomicAdd(&T[t * 4 + 0], ax);
  atomicAdd(&T[t * 4 + 1], ay);
  atomicAdd(&T[t * 4 + 2], az);
  atomicAdd(&T[t * 4 + 3], aw);
}

__global__ __launch_bounds__(256) void mean_k(const float* __restrict__ T,
                                              const float* __restrict__ w1,
                                              float* __restrict__ mean) {
  __shared__ double U8[25][8];
  __shared__ double U[25];
  int t = threadIdx.x;
  if (t < 200) {
    int tap = t >> 3, part = t & 7;
    int ky = tap / 5, kx = tap % 5;
    double s = 0.0;
    for (int p = part * 98; p < part * 98 + 98; ++p) {
      int py = p / 28, px = p % 28;
      s += (double)T[(py + ky) * 32 + px + kx];
    }
    U8[tap][part] = s;
  }
  __syncthreads();
  if (t < 25) {
    double s = 0.0;
    for (int i = 0; i < 8; ++i) s += U8[t][i];
    U[t] = s;
  }
  __syncthreads();
  if (t < 20) {
    double s = 0.0;
    for (int q = 0; q < 25; ++q) s += (double)w1[t * 25 + q] * U[q];
    mean[t] = (float)(s / (8192.0 * 784.0));
  }
}

// thread = (n, 2x2 pooled block): pooled rows 2q,2q+1 x cols 2p,2p+1.
// Patch 8x8 (aligned float4), 16 conv outputs, 400 fma per 25 s_loads.
// Grid: 8192*49/256 = 1568 exact.
__global__ __launch_bounds__(256) void conv1_sign_k(const float* __restrict__ x,
                                                    const float* __restrict__ w1,
                                                    const float* __restrict__ mean,
                                                    uint32_t* __restrict__ b1p) {
  unsigned gid = blockIdx.x * 256 + threadIdx.x;
  unsigned n = gid / 49u;
  unsigned u = gid % 49u;
  unsigned q = u / 7u, pxp = u % 7u;
  const float* base = x + (size_t)n * 1024 + q * 128 + pxp * 4;
  float p[8][8];
#pragma unroll
  for (int r = 0; r < 8; ++r) {
    float4 a = *(const float4*)(base + r * 32);
    float4 b = *(const float4*)(base + r * 32 + 4);
    p[r][0] = a.x; p[r][1] = a.y; p[r][2] = a.z; p[r][3] = a.w;
    p[r][4] = b.x; p[r][5] = b.y; p[r][6] = b.z; p[r][7] = b.w;
  }
  uint32_t m00 = 0, m01 = 0, m10 = 0, m11 = 0;
  for (int c = 0; c < 20; ++c) {
    float s[4][4];
#pragma unroll
    for (int i = 0; i < 4; ++i)
#pragma unroll
      for (int j = 0; j < 4; ++j) s[i][j] = 0.f;
#pragma unroll
    for (int ky = 0; ky < 5; ++ky)
#pragma unroll
      for (int kx = 0; kx < 5; ++kx) {
        float wv = w1[c * 25 + ky * 5 + kx];
#pragma unroll
        for (int dy = 0; dy < 4; ++dy)
#pragma unroll
          for (int dx = 0; dx < 4; ++dx)
            s[dy][dx] += p[ky + dy][kx + dx] * wv;
      }
    float m = mean[c];
    if (s[0][0] > m || s[0][1] > m || s[1][0] > m || s[1][1] > m) m00 |= (1u << c);
    if (s[0][2] > m || s[0][3] > m || s[1][2] > m || s[1][3] > m) m01 |= (1u << c);
    if (s[2][0] > m || s[2][1] > m || s[3][0] > m || s[3][1] > m) m10 |= (1u << c);
    if (s[2][2] > m || s[2][3] > m || s[3][2] > m || s[3][3] > m) m11 |= (1u << c);
  }
  uint32_t* dst = b1p + (size_t)n * 196 + 2 * q * 14 + 2 * pxp;
  uint2 r0; r0.x = m00; r0.y = m01;
  uint2 r1; r1.x = m10; r1.y = m11;
  *(uint2*)dst = r0;
  *(uint2*)(dst + 14) = r1;
}

// Fused conv2+pool/sign+linear+fc. Block = 4 images, one wave per image.
// Single __syncthreads (wsh staging); all other phases are wave-lockstep.
__global__ __launch_bounds__(256) void conv2lin_k(const uint32_t* __restrict__ b1p,
                                                  const uint32_t* __restrict__ wp2,
                                                  const unsigned long long* __restrict__ lwp,
                                                  const float* __restrict__ alpha,
                                                  const float* __restrict__ fcw,
                                                  const float* __restrict__ fcb,
                                                  float* __restrict__ out) {
  __shared__ uint32_t wsh[1250];
  __shared__ uint32_t bm[4][196];
  __shared__ int sumpc[4][100];
  __shared__ signed char s2sh[4][1280];
  __shared__ float hsh[4][512];
  int tid = threadIdx.x;
  int wave = tid >> 6, lane = tid & 63;
  int n = blockIdx.x * 4 + wave;

  for (int i = tid; i < 1250; i += 256) wsh[i] = wp2[i];
  // wave-local bm staging
#pragma unroll
  for (int rd = 0; rd < 4; ++rd) {
    int idx = rd * 64 + lane;
    if (idx < 196) bm[wave][idx] = b1p[(size_t)n * 196 + idx];
  }
  __syncthreads();

  // sumpc: per conv output (10x10), popcount of 5x5 bm window
#pragma unroll
  for (int rd = 0; rd < 2; ++rd) {
    int pp = rd * 64 + lane;
    if (pp < 100) {
      int Y = pp / 10, X = pp % 10, s = 0;
#pragma unroll
      for (int ky = 0; ky < 5; ++ky)
#pragma unroll
        for (int kx = 0; kx < 5; ++kx)
          s += __popc(bm[wave][(Y + ky) * 14 + X + kx]);
      sumpc[wave][pp] = s;
    }
  }

  // conv2: unit = (oc, pooled row r); 5 pooled cols per unit
#pragma unroll
  for (int rd = 0; rd < 4; ++rd) {
    int unit = rd * 64 + lane;
    if (unit < 250) {
      int oc = unit / 5, r = unit % 5;
      uint32_t w[25];
#pragma unroll
      for (int i = 0; i < 25; ++i) w[i] = wsh[oc * 25 + i];
      for (int pc = 0; pc < 5; ++pc) {
        uint32_t pa[6][6];
#pragma unroll
        for (int rr = 0; rr < 6; ++rr)
#pragma unroll
          for (int cc = 0; cc < 6; ++cc)
            pa[rr][cc] = bm[wave][(2 * r + rr) * 14 + 2 * pc + cc];
        int best = -1000000;
#pragma unroll
        for (int dy = 0; dy < 2; ++dy)
#pragma unroll
          for (int dx = 0; dx < 2; ++dx) {
            int a = 0;
#pragma unroll
            for (int ky = 0; ky < 5; ++ky)
#pragma unroll
              for (int kx = 0; kx < 5; ++kx)
                a += __popc(w[ky * 5 + kx] & pa[dy + ky][dx + kx]);
            a = 2 * a - sumpc[wave][(2 * r + dy) * 10 + 2 * pc + dx];
            if (a > best) best = a;
          }
        s2sh[wave][5 * unit + pc] = (signed char)((best > 0) - (best < 0));
      }
    }
  }
  if (lane < 30) s2sh[wave][1250 + lane] = 0;

  // ballot-pack signs; P/N masks stay wave-uniform in registers
  unsigned long long Pm[20], Nm[20];
  int cp = 0, cn = 0;
#pragma unroll
  for (int k = 0; k < 20; ++k) {
    signed char v = s2sh[wave][k * 64 + lane];
    unsigned long long P = __ballot(v > 0);
    unsigned long long N = __ballot(v < 0);
    Pm[k] = P; Nm[k] = N;
    cp += __popcll(P); cn += __popcll(N);
  }

  // binary linear 1250->500 + clip
#pragma unroll
  for (int rd = 0; rd < 8; ++rd) {
    int j = rd * 64 + lane;
    float y = 0.f;
    if (j < 500) {
      const ulonglong2* W2 = (const ulonglong2*)(lwp + (size_t)j * 20);
      int a = 0, b = 0;
#pragma unroll
      for (int i = 0; i < 10; ++i) {
        ulonglong2 w2v = W2[i];
        a += __popcll(w2v.x & Pm[2 * i]) + __popcll(w2v.y & Pm[2 * i + 1]);
        b += __popcll(w2v.x & Nm[2 * i]) + __popcll(w2v.y & Nm[2 * i + 1]);
      }
      int dot = 2 * (a - b) - cp + cn;
      y = alpha[j] * (float)dot;
      y = fminf(1.0f, fmaxf(-1.0f, y));
    }
    hsh[wave][rd * 64 + lane] = y;
  }

  // fc 500->10, wave shuffle reduce
  float hv[8];
#pragma unroll
  for (int k = 0; k < 8; ++k) hv[k] = hsh[wave][k * 64 + lane];
#pragma unroll
  for (int o = 0; o < 10; ++o) {
    float pa = 0.f;
#pragma unroll
    for (int k = 0; k < 8; ++k) {
      int j = k * 64 + lane;
      if (j < 500) pa += hv[k] * fcw[o * 500 + j];
    }
    for (int off = 32; off > 0; off >>= 1) pa += __shfl_down(pa, off, 64);
    if (lane == 0) out[(size_t)n * 10 + o] = pa + fcb[o];
  }
}

extern "C" void kernel_launch(void* const* d_in, const int* in_sizes, int n_in,
                              void* d_out, int out_size, void* d_ws, size_t ws_size,
                              hipStream_t stream) {
  const float* x   = (const float*)d_in[0];
  const float* w1  = (const float*)d_in[1];
  const float* w2  = (const float*)d_in[2];
  const float* lw  = (const float*)d_in[3];
  const float* fcw = (const float*)d_in[4];
  const float* fcb = (const float*)d_in[5];
  float* out = (float*)d_out;
  char* ws = (char*)d_ws;

  float*    T     = (float*)(ws + 0);
  float*    mean  = (float*)(ws + 4096);
  uint32_t* wp2   = (uint32_t*)(ws + 4224);
  float*    alpha = (float*)(ws + 9344);
  unsigned long long* lwp = (unsigned long long*)(ws + 11392);
  uint32_t* b1p   = (uint32_t*)(ws + 91392);

  hipMemsetAsync(T, 0, 1024 * sizeof(float), stream);
  prep_k<<<520, 64, 0, stream>>>(lw, w2, lwp, alpha, wp2);
  sumT_k<<<256, 256, 0, stream>>>(x, T);
  mean_k<<<1, 256, 0, stream>>>(T, w1, mean);
  conv1_sign_k<<<1568, 256, 0, stream>>>(x, w1, mean, b1p);
  conv2lin_k<<<2048, 256, 0, stream>>>(b1p, wp2, lwp, alpha, fcw, fcb, out);
}